// Round 8
// baseline (615.523 us; speedup 1.0000x reference)
//
#include <hip/hip_runtime.h>
#include <stdint.h>

#define N_SAMP 131072
#define DIN    256
#define HIDN   1024
#define BROWS  256           // rows per block, 64 per wave; 512 blocks = 2/CU exactly
#define NTHREADS 256         // 4 waves/block
#define NCHUNK 16            // 16 chunks of 64 hidden cols

typedef __attribute__((ext_vector_type(8))) short short8;
typedef __attribute__((ext_vector_type(4))) float f32x4;

__device__ __forceinline__ unsigned short f2bf(float f) {
  unsigned u = __float_as_uint(f);
  u += 0x7fffu + ((u >> 16) & 1u);   // round-to-nearest-even (inputs finite)
  return (unsigned short)(u >> 16);
}

__device__ __forceinline__ short8 pack8(float4 a, float4 b) {
  short8 r;
  r[0] = (short)f2bf(a.x); r[1] = (short)f2bf(a.y);
  r[2] = (short)f2bf(a.z); r[3] = (short)f2bf(a.w);
  r[4] = (short)f2bf(b.x); r[5] = (short)f2bf(b.y);
  r[6] = (short)f2bf(b.z); r[7] = (short)f2bf(b.w);
  return r;
}

// Pre-pack W1 (fp32 [1024][256]) into bf16 MFMA-fragment order (512 KB).
// Fragment index idx = ((ch*8 + s)*4 + nt)*64 + lane ; each frag = 16 B.
// Lane l of frag (ch,s,nt) holds W1[ch*64 + nt*16 + (l&15)][s*32 + (l>>4)*8 .. +8].
// Verified correct in r6/r7 (absmax 0.0039, passed).
__global__ __launch_bounds__(256) void w1_pack(const float* __restrict__ W1,
                                               unsigned short* __restrict__ o) {
  int idx = blockIdx.x * 256 + threadIdx.x;   // 32768 frags
  int l  = idx & 63;
  int nt = (idx >> 6) & 3;
  int s  = (idx >> 8) & 7;
  int ch = idx >> 11;
  int col = ch * 64 + nt * 16 + (l & 15);
  int k0  = s * 32 + (l >> 4) * 8;
  const float* src = W1 + (size_t)col * DIN + k0;
  float4 f0 = *(const float4*)src;
  float4 f1 = *(const float4*)(src + 4);
  ((short8*)o)[idx] = pack8(f0, f1);
}

// Fused: h = relu(x@W1^T + b1); y = dot(We[c[num]], h) + be[...]; out = sigmoid(y)
//
// History (r0-r7):
//  - r0: LDS dbuf + barrier, swizzled row-major: 119us, 8.4M conflicts.
//  - r1/r3/r4: every 512-thr occupancy spelling -> VGPR clamp 64 + spill.
//  - r2: smaller chunks/more blocks: occupancy did not rise; slower (129us).
//  - r5: t=4 under launch_bounds(256,2) -> clamp 128 + spill (320us).
//  - r6: no LDS, B from L2, 0 barriers: conflicts 0 but L2 latency exposed, 164us.
//  - r7: r0 frame + fragment-packed LDS: conflicts 8.4M->0, VGPR 120, dur
//        UNCHANGED 119us -> LDS conflicts were absorbed slack, not critical.
//        Diffuse latency at 2 waves/SIMD is the wall; occupancy axis is dead.
//
// r8 (this): amortize instead — 64 rows/wave (t=4), HALF the blocks ->
// total LDS B-reads halve (1/(rows-per-wave) scaling), barrier rounds/CU
// halve, 512 blocks = exactly 2/CU resident (no tail). Register budget:
// afr[4][8]=128 + bfr 8 + yacc/eoff 32 + misc ~= 190 arch VGPRs, acc in
// AGPRs. NO __launch_bounds__ — r5's clamp came from the (256,2) bound;
// default bounds allocate naturally (m08: no spill through 450 regs), and
// ~190 regs is 2 waves/SIMD anyway (m69 steps at 128/256) = zero occupancy
// cost. Half-pass epilogue keeps live acc at 32.
// go/no-go: VGPR_Count 180-220 (128+FETCH>200MB = clamp -> revert to r7+
// gather-prefetch; ~256 = 1 wave/SIMD, expect occ ~10% and regression).
template <bool WBF>
__global__ void fused_kernel(
    const float* __restrict__ x,
    const float* __restrict__ W1f,
    const unsigned short* __restrict__ W1p,  // packed fragments (WBF)
    const float* __restrict__ b1,
    const float* __restrict__ We,   // [100][1024]
    const float* __restrict__ be,   // [100]
    const int* __restrict__ num,    // [N]
    const int* __restrict__ c,      // [100]
    float* __restrict__ out)        // [N]
{
  __shared__ unsigned short Wt[2][16384];  // 2 x 32 KB, fragment order
  __shared__ int e_sh[BROWS];              // 1 KB

  const int tid  = threadIdx.x;
  const int lane = tid & 63;
  const int w    = tid >> 6;        // wave 0..3
  const int n    = lane & 15;       // MFMA m/n lane coord
  const int quad = lane >> 4;       // 0..3
  const int R0   = blockIdx.x * BROWS;

  if (tid < BROWS) e_sh[tid] = c[num[R0 + tid]];

  // ---- A fragments: 4 row-tiles x 8 k-steps, register-resident (128 VGPRs).
  // A[m=lane&15][k=quad*8+j]; k0 = s*32 + quad*8.
  short8 afr[4][8];
  {
    const float* xr0 = x + (size_t)(R0 + w * 64 + n) * DIN + quad * 8;
#pragma unroll
    for (int t = 0; t < 4; ++t) {
      const float* xr = xr0 + (size_t)t * 16 * DIN;
#pragma unroll
      for (int s = 0; s < 8; ++s) {
        float4 f0 = *(const float4*)(xr + s * 32);
        float4 f1 = *(const float4*)(xr + s * 32 + 4);
        afr[t][s] = pack8(f0, f1);
      }
    }
  }

  // ---- stage chunk 0 into buf 0 (32 x 1KB linear spans, 8 per wave)
  if (WBF) {
#pragma unroll
    for (int j = 0; j < 8; ++j) {
      int inst = w * 8 + j;                 // 0..31
      const unsigned short* g = W1p + inst * 512 + lane * 8;
      __builtin_amdgcn_global_load_lds(
          (const __attribute__((address_space(1))) unsigned int*)g,
          (__attribute__((address_space(3))) unsigned int*)(&Wt[0][0] + inst * 512),
          16, 0, 0);
    }
  } else {
    // fallback: pack fp32 W1 into fragment-order LDS by hand
#pragma unroll
    for (int j = 0; j < 8; ++j) {
      int id = tid + j * NTHREADS;          // 0..2047 = frag*64 + lane
      int l = id & 63, f = id >> 6;         // f = s*4+nt within chunk 0
      int nt = f & 3, s = f >> 2;
      int col = nt * 16 + (l & 15);
      int k0  = s * 32 + (l >> 4) * 8;
      const float* gs = W1f + (size_t)col * DIN + k0;
      float4 f0 = *(const float4*)gs;
      float4 f1 = *(const float4*)(gs + 4);
      *(short8*)&Wt[0][f * 512 + l * 8] = pack8(f0, f1);
    }
  }

  __syncthreads();  // e_sh + chunk 0 ready

  int eoff[4][4];
#pragma unroll
  for (int t = 0; t < 4; ++t)
#pragma unroll
    for (int r = 0; r < 4; ++r)
      eoff[t][r] = e_sh[w * 64 + t * 16 + quad * 4 + r] * HIDN;

  float yacc[4][4];
#pragma unroll
  for (int t = 0; t < 4; ++t)
#pragma unroll
    for (int r = 0; r < 4; ++r) yacc[t][r] = 0.f;

  int buf = 0;
  for (int ch = 0; ch < NCHUNK; ++ch) {
    // ---- async-stage next chunk into the other buffer (lands during compute)
    if (ch + 1 < NCHUNK) {
      if (WBF) {
        const unsigned short* Wg = W1p + (size_t)(ch + 1) * 16384;
        unsigned short* db = &Wt[buf ^ 1][0];
#pragma unroll
        for (int j = 0; j < 8; ++j) {
          int inst = w * 8 + j;
          const unsigned short* g = Wg + inst * 512 + lane * 8;
          __builtin_amdgcn_global_load_lds(
              (const __attribute__((address_space(1))) unsigned int*)g,
              (__attribute__((address_space(3))) unsigned int*)(db + inst * 512),
              16, 0, 0);
        }
      } else {
        const float* Wc = W1f + (size_t)(ch + 1) * 64 * DIN;
#pragma unroll
        for (int j = 0; j < 8; ++j) {
          int id = tid + j * NTHREADS;
          int l = id & 63, f = id >> 6;
          int nt = f & 3, s = f >> 2;
          int col = nt * 16 + (l & 15);
          int k0  = s * 32 + (l >> 4) * 8;
          const float* gs = Wc + (size_t)col * DIN + k0;
          float4 f0 = *(const float4*)gs;
          float4 f1 = *(const float4*)(gs + 4);
          *(short8*)&Wt[buf ^ 1][f * 512 + l * 8] = pack8(f0, f1);
        }
      }
    }

    // ---- MFMA over this chunk: 4 row-tiles x 4 col-tiles, K=256, in two
    // 32-col half-passes (live acc = 32 regs). B-frag (s,nt) at byte offset
    // (s*4+nt)*1024 + lane*16 — base+immediate ds_read_b128, conflict-free.
    const char* Bbase = (const char*)&Wt[buf][0] + lane * 16;

#pragma unroll
    for (int half = 0; half < 2; ++half) {
      f32x4 acc[4][2];
#pragma unroll
      for (int t = 0; t < 4; ++t)
#pragma unroll
        for (int nn = 0; nn < 2; ++nn)
          acc[t][nn] = (f32x4){0.f, 0.f, 0.f, 0.f};

#pragma unroll
      for (int s = 0; s < 8; ++s) {
        short8 bfr[2];
#pragma unroll
        for (int nn = 0; nn < 2; ++nn)
          bfr[nn] = *(const short8*)(Bbase + (s * 4 + half * 2 + nn) * 1024);
#pragma unroll
        for (int t = 0; t < 4; ++t)
#pragma unroll
          for (int nn = 0; nn < 2; ++nn)
            acc[t][nn] = __builtin_amdgcn_mfma_f32_16x16x32_bf16(
                afr[t][s], bfr[nn], acc[t][nn], 0, 0, 0);
      }

      // ---- epilogue: +b1, relu, * gathered We row, accumulate y
      // C layout: col(n) = lane&15, row = quad*4 + reg  [m89/m91]
#pragma unroll
      for (int nn = 0; nn < 2; ++nn) {
        int col = ch * 64 + (half * 2 + nn) * 16 + n;
        float bv = b1[col];
        const float* Wec = We + col;
#pragma unroll
        for (int t = 0; t < 4; ++t)
#pragma unroll
          for (int r = 0; r < 4; ++r) {
            float h = acc[t][nn][r] + bv;
            h = fmaxf(h, 0.f);
            yacc[t][r] = fmaf(h, Wec[eoff[t][r]], yacc[t][r]);
          }
      }
    }

    __syncthreads();  // all reads of buf done; next-chunk staging drained
    buf ^= 1;
  }

  // ---- reduce partial y across the 16 n-lanes of each quad group
#pragma unroll
  for (int t = 0; t < 4; ++t)
#pragma unroll
    for (int r = 0; r < 4; ++r) {
      float v = yacc[t][r];
      v += __shfl_xor(v, 1);
      v += __shfl_xor(v, 2);
      v += __shfl_xor(v, 4);
      v += __shfl_xor(v, 8);
      yacc[t][r] = v;
    }

  if (n == 0) {
#pragma unroll
    for (int t = 0; t < 4; ++t)
#pragma unroll
      for (int r = 0; r < 4; ++r) {
        int row = R0 + w * 64 + t * 16 + quad * 4 + r;
        float yy = yacc[t][r] + be[eoff[t][r] >> 10];  // eoff / HIDN
        out[row] = 1.f / (1.f + __expf(-yy));
      }
  }
}

extern "C" void kernel_launch(void* const* d_in, const int* in_sizes, int n_in,
                              void* d_out, int out_size, void* d_ws, size_t ws_size,
                              hipStream_t stream) {
  const float* x   = (const float*)d_in[0];
  const float* W1  = (const float*)d_in[1];
  const float* b1  = (const float*)d_in[2];
  const float* We  = (const float*)d_in[3];
  const float* be  = (const float*)d_in[4];
  const int*   num = (const int*)d_in[5];
  const int*   c   = (const int*)d_in[6];
  float* out = (float*)d_out;

  const size_t w1p_bytes = (size_t)HIDN * DIN * sizeof(unsigned short);  // 512 KB
  const bool usebf = ws_size >= w1p_bytes;
  unsigned short* w1p = (unsigned short*)d_ws;

  if (usebf) {
    w1_pack<<<dim3((HIDN * DIN / 8) / 256), dim3(256), 0, stream>>>(W1, w1p);
    fused_kernel<true><<<dim3(N_SAMP / BROWS), dim3(NTHREADS), 0, stream>>>(
        x, W1, w1p, b1, We, be, num, c, out);
  } else {
    fused_kernel<false><<<dim3(N_SAMP / BROWS), dim3(NTHREADS), 0, stream>>>(
        x, W1, w1p, b1, We, be, num, c, out);
  }
}